// Round 6
// baseline (657.215 us; speedup 1.0000x reference)
//
#include <hip/hip_runtime.h>
#include <math.h>

// Program interpreter: B=1M rows, 19 steps of MLP(2->64->64->3) + argmax walk.
// fp32 emulated on f16 MFMA, 2-limb splits (lo limb scaled 2^12, RTZ pack).
//
// R14: fine-grained MFMA/VALU interleave. Corrected model: VALUBusy includes
// MFMA on CDNA; R8's real breakdown per SIMD-step (2700cyc) = MFMA-pipe 930
// + true-VALU 810 + ~950 idle. The idle is a GRANULARITY problem: the step
// is one 466-cyc pure-MFMA block + one pure-VALU block per wave; in-order
// issue blocks a wave's own VALU behind its MFMA queue, and both waves
// traverse the same coarse blocks. Fix: stage the step as alternating small
// MFMA-trio / VALU windows fenced by sched_barrier(0) so the scheduler can't
// re-coalesce them: L1kf0 | kf0 trios + L1kf1 | kf1 trios t0,t1 |
// t2 trio + combine/dot t0 | t3 trio + combine/dot t1 | tail. Tail reduce
// moved to permlane16/32_swap (VALU latency ~8cyc vs DS ~120; R9-proven
// bitwise-identical association). ALL arithmetic associations identical to
// the 632us R8 kernel -> absmax must be exactly 0.00390625.

#define NSTEPS 19

typedef _Float16 half8   __attribute__((ext_vector_type(8)));
typedef _Float16 half2v  __attribute__((ext_vector_type(2)));
typedef float    float2v __attribute__((ext_vector_type(2)));
typedef float    float4v __attribute__((ext_vector_type(4)));
typedef unsigned int uint2v __attribute__((ext_vector_type(2)));

__device__ __forceinline__ half2v pkrtz(float a, float b) {
    return __builtin_bit_cast(half2v, __builtin_amdgcn_cvt_pkrtz(a, b));
}
__device__ __forceinline__ float2v lo2(float4v v) {
    return __builtin_shufflevector(v, v, 0, 1);
}
__device__ __forceinline__ float2v hi2(float4v v) {
    return __builtin_shufflevector(v, v, 2, 3);
}

// Sum over the 4 k-replica groups, association (x+x^16)+(x^32+x^48) --
// identical to the R8 DS butterfly (R9-validated: same absmax). VALU-pipe
// latency (~8cyc/inst) instead of DS (~120cyc/hop): matters now that the
// reduce sits on the exposed serial tail of the pipelined step.
__device__ __forceinline__ float xsum48(float g) {
#if __has_builtin(__builtin_amdgcn_permlane16_swap) && \
    __has_builtin(__builtin_amdgcn_permlane32_swap)
    unsigned u = __builtin_bit_cast(unsigned, g);
    uint2v a = __builtin_amdgcn_permlane16_swap(u, u, false, false);
    g = __builtin_bit_cast(float, (unsigned)a[0]) +
        __builtin_bit_cast(float, (unsigned)a[1]);
    unsigned v = __builtin_bit_cast(unsigned, g);
    uint2v b = __builtin_amdgcn_permlane32_swap(v, v, false, false);
    return __builtin_bit_cast(float, (unsigned)b[0]) +
           __builtin_bit_cast(float, (unsigned)b[1]);
#else
    int r = __builtin_amdgcn_ds_swizzle(__builtin_bit_cast(int, g), 0x401F);
    g += __builtin_bit_cast(float, r);
    g += __shfl_xor(g, 32, 64);
    return g;
#endif
}

__global__ __launch_bounds__(256, 2)
void program_kernel(const float* __restrict__ x,
                    const float* __restrict__ W1,
                    const float* __restrict__ b1,
                    const float* __restrict__ W2,
                    const float* __restrict__ b2,
                    const float* __restrict__ W3,
                    const float* __restrict__ b3,
                    float* __restrict__ out,
                    int B) {
    const int tid    = threadIdx.x;
    const int lane   = tid & 63;
    const int wave   = tid >> 6;
    const int lanelo = lane & 15;   // m: my batch row within the tile
    const int q8     = lane >> 4;   // k-slice / replica group 0..3
    const int myRow  = blockIdx.x * 64 + wave * 16 + lanelo;
    const int rowLd  = myRow < B ? myRow : (B - 1);

    // ---- w1 tables as pairs (VGPR): pair i of kf-half: k = kf*32+q8*8+2i ----
    float2v w1a[8], w1b[8], b1v[8];
    #pragma unroll
    for (int kf = 0; kf < 2; ++kf) {
        const int k0 = kf * 32 + q8 * 8;
        const float2v* a = (const float2v*)(W1 + k0);
        const float2v* bb = (const float2v*)(W1 + 64 + k0);
        const float2v* bv = (const float2v*)(b1 + k0);
        #pragma unroll
        for (int i = 0; i < 4; ++i) {
            w1a[kf * 4 + i] = a[i];
            w1b[kf * 4 + i] = bb[i];
            b1v[kf * 4 + i] = bv[i];
        }
    }

    // ---- W2^T limb A-frags (MFMA-only; AGPR-eligible) ----
    half8 Wh[2][4], Wl[2][4];
    #pragma unroll
    for (int kf = 0; kf < 2; ++kf) {
        #pragma unroll
        for (int t = 0; t < 4; ++t) {
            half8 bh, bl;
            #pragma unroll
            for (int j = 0; j < 8; ++j) {
                const float w =
                    W2[(kf * 32 + q8 * 8 + j) * 64 + t * 16 + lanelo];
                const _Float16 wh = (_Float16)w;                       // RNE
                const _Float16 wl = (_Float16)((w - (float)wh) * 4096.0f);
                bh[j] = wh;
                bl[j] = wl;
            }
            Wh[kf][t] = bh;
            Wl[kf][t] = bl;
        }
    }

    // ---- b2 C-init frags (MFMA-C only) ----
    float4v b2f[4];
    #pragma unroll
    for (int t = 0; t < 4; ++t) {
        const int n = t * 16 + q8 * 4;
        b2f[t] = (float4v){b2[n], b2[n + 1], b2[n + 2], b2[n + 3]};
    }

    // ---- W3 difference tables (VGPR): my n-set n = 16t+4*q8+r, pairs ----
    float2v d10[8], d20[8];
    #pragma unroll
    for (int p = 0; p < 8; ++p) {
        const int n0 = (p >> 1) * 16 + q8 * 4 + (p & 1) * 2;
        const float w00 = W3[n0 * 3 + 0],       w01 = W3[n0 * 3 + 1];
        const float w02 = W3[n0 * 3 + 2];
        const float w10 = W3[(n0 + 1) * 3 + 0], w11 = W3[(n0 + 1) * 3 + 1];
        const float w12 = W3[(n0 + 1) * 3 + 2];
        d10[p] = (float2v){w01 - w00, w11 - w10};
        d20[p] = (float2v){w02 - w00, w12 - w10};
    }
    const float b3v0 = b3[0];
    const float db10 = b3[1] - b3[0];
    const float db20 = b3[2] - b3[0];

    // ---- initial row state (4x replicated across q8 groups) ----
    float pos, fwd, c5;
    {
        const float* xr = x + (size_t)rowLd * 6;
        pos = xr[0];
        fwd = xr[1];
        c5  = xr[5];
    }

    const float4v zf = {0.f, 0.f, 0.f, 0.f};
    const float2v z2 = {0.f, 0.f};
    const float2v kinv = {1.0f / 4096.0f, 1.0f / 4096.0f};
    float l0 = 0.f, l1 = 0.f, l2 = 0.f;

    // L1 half: identical math to R8's per-kf body.
    #define L1HALF(KF, HH, HL)                                                \
        {                                                                     \
            union { half8 v; half2v h2[4]; } uh, ul;                          \
            _Pragma("unroll")                                                 \
            for (int p = 0; p < 4; ++p) {                                     \
                const int e = (KF) * 4 + p;                                   \
                float2v z = __builtin_elementwise_fma(fwdp, w1b[e], b1v[e]);  \
                z = __builtin_elementwise_fma(posp, w1a[e], z);               \
                const float2v hp = __builtin_elementwise_max(z, z2);          \
                uh.h2[p] = pkrtz(hp[0], hp[1]);                               \
                const float r0 = fmaf((float)uh.h2[p][0], -1.0f, hp[0]);      \
                const float r1 = fmaf((float)uh.h2[p][1], -1.0f, hp[1]);      \
                const float2v rp = (float2v){r0, r1} * 4096.0f;               \
                ul.h2[p] = pkrtz(rp[0], rp[1]);                               \
            }                                                                 \
            HH = uh.v;                                                        \
            HL = ul.v;                                                        \
        }

    // kf0 trio for tile t: starts both acc chains (R8 order).
    #define TRIO0(T)                                                          \
        accB[T] = __builtin_amdgcn_mfma_f32_16x16x32_f16(                     \
            Wl[0][T], Hh0, zf, 0, 0, 0);                                      \
        accB[T] = __builtin_amdgcn_mfma_f32_16x16x32_f16(                     \
            Wh[0][T], Hl0, accB[T], 0, 0, 0);                                 \
        accA[T] = __builtin_amdgcn_mfma_f32_16x16x32_f16(                     \
            Wh[0][T], Hh0, b2f[T], 0, 0, 0);

    // kf1 trio for tile t: finishes both acc chains (R8 order).
    #define TRIO1(T)                                                          \
        accB[T] = __builtin_amdgcn_mfma_f32_16x16x32_f16(                     \
            Wl[1][T], Hh1, accB[T], 0, 0, 0);                                 \
        accB[T] = __builtin_amdgcn_mfma_f32_16x16x32_f16(                     \
            Wh[1][T], Hl1, accB[T], 0, 0, 0);                                 \
        accA[T] = __builtin_amdgcn_mfma_f32_16x16x32_f16(                     \
            Wh[1][T], Hh1, accA[T], 0, 0, 0);

    // combine + diff-dot for tile t; s1/s2 chain in tile order (== R8's
    // p=0..7 order, bitwise identical). h2p kept for last-step reuse.
    #define CMBDOT(T)                                                         \
        h2p[2 * (T)] = __builtin_elementwise_max(                             \
            __builtin_elementwise_fma(lo2(accB[T]), kinv, lo2(accA[T])), z2); \
        h2p[2 * (T) + 1] = __builtin_elementwise_max(                         \
            __builtin_elementwise_fma(hi2(accB[T]), kinv, hi2(accA[T])), z2); \
        s1 = __builtin_elementwise_fma(h2p[2 * (T)], d10[2 * (T)], s1);       \
        s1 = __builtin_elementwise_fma(h2p[2 * (T) + 1], d10[2 * (T) + 1],    \
                                       s1);                                   \
        s2 = __builtin_elementwise_fma(h2p[2 * (T)], d20[2 * (T)], s2);       \
        s2 = __builtin_elementwise_fma(h2p[2 * (T) + 1], d20[2 * (T) + 1],    \
                                       s2);

    #pragma unroll 1
    for (int step = 0; step < NSTEPS; ++step) {
        const float2v posp = {pos, pos}, fwdp = {fwd, fwd};
        half8 Hh0, Hl0, Hh1, Hl1;
        float4v accA[4], accB[4];
        float2v h2p[8];
        float2v s1 = z2, s2 = z2;

        // ---- S1: L1 kf=0 ----
        L1HALF(0, Hh0, Hl0);
        __builtin_amdgcn_sched_barrier(0);

        // ---- S2: kf0 MFMA trios, L1 kf=1 interleaved ----
        TRIO0(0);
        L1HALF(1, Hh1, Hl1);
        TRIO0(1);
        TRIO0(2);
        TRIO0(3);
        __builtin_amdgcn_sched_barrier(0);

        // ---- S3: kf1 trios t0, t1 ----
        TRIO1(0);
        TRIO1(1);
        __builtin_amdgcn_sched_barrier(0);

        // ---- S4: kf1 trio t2  ||  combine+dot t0 ----
        TRIO1(2);
        CMBDOT(0);
        __builtin_amdgcn_sched_barrier(0);

        // ---- S5: kf1 trio t3  ||  combine+dot t1 ----
        TRIO1(3);
        CMBDOT(1);
        __builtin_amdgcn_sched_barrier(0);

        // ---- S6: tail: combine t2,t3; reduce; decision ----
        CMBDOT(2);
        CMBDOT(3);

        float g10 = xsum48(s1[0] + s1[1]) + db10;   // = l1 - l0
        float g20 = xsum48(s2[0] + s2[1]) + db20;   // = l2 - l0

        // ---- last step: reconstruct full logits for the output probs ----
        if (step == NSTEPS - 1) {
            float2v s0 = z2;
            #pragma unroll
            for (int p = 0; p < 8; ++p) {
                const int n0 = (p >> 1) * 16 + q8 * 4 + (p & 1) * 2;
                const float2v w30 = {W3[n0 * 3], W3[(n0 + 1) * 3]};
                s0 = __builtin_elementwise_fma(h2p[p], w30, s0);
            }
            l0 = xsum48(s0[0] + s0[1]) + b3v0;
            l1 = l0 + g10;
            l2 = l0 + g20;
        }

        // ---- decision: l2 > max(l0,l1) <=> g20 > max(0,g10);
        //      l1 > l0 <=> g10 > 0 (first-max-wins preserved) ----
        const float delta =
            (g20 > fmaxf(0.f, g10)) ? 1.0f : ((g10 > 0.f) ? 0.0f : -1.0f);
        pos += delta;
        fwd += 1.0f;
    }

    // ---- epilogue: all lanes have their row's logits; q8==0 stores ----
    if (q8 == 0 && myRow < B) {
        const float p0 = 1.f / (1.f + __expf(-l0));
        const float p1 = 1.f / (1.f + __expf(-l1));
        const float p2 = 1.f / (1.f + __expf(-l2));
        float2* o = (float2*)(out + (size_t)myRow * 6);
        o[0] = make_float2(pos, fwd);
        o[1] = make_float2(p0, p1);
        o[2] = make_float2(p2, c5 + (float)NSTEPS);
    }
}

extern "C" void kernel_launch(void* const* d_in, const int* in_sizes, int n_in,
                              void* d_out, int out_size, void* d_ws, size_t ws_size,
                              hipStream_t stream) {
    const float* x  = (const float*)d_in[0];
    const float* W1 = (const float*)d_in[1];
    const float* b1 = (const float*)d_in[2];
    const float* W2 = (const float*)d_in[3];
    const float* b2 = (const float*)d_in[4];
    const float* W3 = (const float*)d_in[5];
    const float* b3 = (const float*)d_in[6];
    float* out = (float*)d_out;

    const int B = in_sizes[0] / 6;              // 1048576
    const int nBlocks = (B + 63) / 64;          // 64 rows/block (4 waves x 16)

    program_kernel<<<nBlocks, 256, 0, stream>>>(
        x, W1, b1, W2, b2, W3, b3, out, B);
}